// Round 2
// 497.762 us; speedup vs baseline: 1.0821x; 1.0821x over previous
//
#include <hip/hip_runtime.h>

// Guided filter r=8, eps=1e-4, (1,3,4096,4096) fp32.
// Wave-autonomous streaming: no LDS tiles, no barriers.
//  - lane = column (48 outputs + 2*8 halo per 64-lane wave)
//  - vertical 17-row running sums in registers (17-row register circular
//    buffer of I,P; inner 17-iter loop fully unrolled -> constant indices)
//  - horizontal 17-tap box sum via wave-wide DPP inclusive scan +
//    2 ds_bpermute taps per quantity
// This revision: single-instruction v_add_f32_dpp scans (inline asm, 4-way
// interleaved), wave-uniform row addressing via readfirstlane (saddr loads),
// fma halo mask, med3 clamp, 8 blocks/CU.

#define HH   4096
#define WW   4096
#define CC   3
#define RAD  8
#define LOG2W 12
#define OUTW 48            // output columns per wave
#define ROWS 69            // output rows per wave tile (1 + 4*17)
#define CS   86            // ceil(4096/48) column strips
#define RS   60            // ceil(4096/69) row strips
#define WPB  4             // waves per 256-thread block
#define EPS  1e-4f

// Four wave64 inclusive prefix sums, fused-DPP, manually 4-way interleaved.
// Interleaving gives every dpp instruction >=3 instructions of distance from
// the write of its source (covers the 2-wait-state VALU->DPP hazard), and the
// leading movs insulate the first dpp reads from whatever the compiler
// emitted just before the block.
__device__ __forceinline__ void scan4(float si, float sp, float spi, float sii,
                                      float& a, float& b, float& c, float& d) {
    asm("v_mov_b32 %0, %4\n\t"
        "v_mov_b32 %1, %5\n\t"
        "v_mov_b32 %2, %6\n\t"
        "v_mov_b32 %3, %7\n\t"
        "v_add_f32_dpp %0, %0, %0 row_shr:1 row_mask:0xf bank_mask:0xf bound_ctrl:0\n\t"
        "v_add_f32_dpp %1, %1, %1 row_shr:1 row_mask:0xf bank_mask:0xf bound_ctrl:0\n\t"
        "v_add_f32_dpp %2, %2, %2 row_shr:1 row_mask:0xf bank_mask:0xf bound_ctrl:0\n\t"
        "v_add_f32_dpp %3, %3, %3 row_shr:1 row_mask:0xf bank_mask:0xf bound_ctrl:0\n\t"
        "v_add_f32_dpp %0, %0, %0 row_shr:2 row_mask:0xf bank_mask:0xf bound_ctrl:0\n\t"
        "v_add_f32_dpp %1, %1, %1 row_shr:2 row_mask:0xf bank_mask:0xf bound_ctrl:0\n\t"
        "v_add_f32_dpp %2, %2, %2 row_shr:2 row_mask:0xf bank_mask:0xf bound_ctrl:0\n\t"
        "v_add_f32_dpp %3, %3, %3 row_shr:2 row_mask:0xf bank_mask:0xf bound_ctrl:0\n\t"
        "v_add_f32_dpp %0, %0, %0 row_shr:4 row_mask:0xf bank_mask:0xf bound_ctrl:0\n\t"
        "v_add_f32_dpp %1, %1, %1 row_shr:4 row_mask:0xf bank_mask:0xf bound_ctrl:0\n\t"
        "v_add_f32_dpp %2, %2, %2 row_shr:4 row_mask:0xf bank_mask:0xf bound_ctrl:0\n\t"
        "v_add_f32_dpp %3, %3, %3 row_shr:4 row_mask:0xf bank_mask:0xf bound_ctrl:0\n\t"
        "v_add_f32_dpp %0, %0, %0 row_shr:8 row_mask:0xf bank_mask:0xf bound_ctrl:0\n\t"
        "v_add_f32_dpp %1, %1, %1 row_shr:8 row_mask:0xf bank_mask:0xf bound_ctrl:0\n\t"
        "v_add_f32_dpp %2, %2, %2 row_shr:8 row_mask:0xf bank_mask:0xf bound_ctrl:0\n\t"
        "v_add_f32_dpp %3, %3, %3 row_shr:8 row_mask:0xf bank_mask:0xf bound_ctrl:0\n\t"
        "v_add_f32_dpp %0, %0, %0 row_bcast:15 row_mask:0xa bank_mask:0xf\n\t"
        "v_add_f32_dpp %1, %1, %1 row_bcast:15 row_mask:0xa bank_mask:0xf\n\t"
        "v_add_f32_dpp %2, %2, %2 row_bcast:15 row_mask:0xa bank_mask:0xf\n\t"
        "v_add_f32_dpp %3, %3, %3 row_bcast:15 row_mask:0xa bank_mask:0xf\n\t"
        "v_add_f32_dpp %0, %0, %0 row_bcast:31 row_mask:0xc bank_mask:0xf\n\t"
        "v_add_f32_dpp %1, %1, %1 row_bcast:31 row_mask:0xc bank_mask:0xf\n\t"
        "v_add_f32_dpp %2, %2, %2 row_bcast:31 row_mask:0xc bank_mask:0xf\n\t"
        "v_add_f32_dpp %3, %3, %3 row_bcast:31 row_mask:0xc bank_mask:0xf"
        : "=&v"(a), "=&v"(b), "=&v"(c), "=&v"(d)
        : "v"(si), "v"(sp), "v"(spi), "v"(sii));
}

// 17-wide window sum from inclusive prefix: Pref[l+8] - Pref[l-9].
// nmsk is -1.0 where the upper tap is valid, 0.0 otherwise (lanes < 9).
__device__ __forceinline__ float win17(float pref, int a_dn, int a_up, float nmsk) {
    float dn = __int_as_float(__builtin_amdgcn_ds_bpermute(a_dn, __float_as_int(pref)));
    float up = __int_as_float(__builtin_amdgcn_ds_bpermute(a_up, __float_as_int(pref)));
    return fmaf(nmsk, up, dn);
}

__global__ __launch_bounds__(256, 8)
void gf_stream_kernel(const float* __restrict__ gi,
                      const float* __restrict__ gp,
                      float* __restrict__ gq) {
    const int lane = threadIdx.x & 63;
    // wave-uniform by construction; readfirstlane makes the compiler see it,
    // so y/row-bases land in SGPRs and loads use saddr+voffset (0 VALU addr math)
    const int wid  = __builtin_amdgcn_readfirstlane(blockIdx.x * WPB + (threadIdx.x >> 6));

    const int c   = wid / (CS * RS);
    const int rm  = wid - c * (CS * RS);
    const int rs  = rm / CS;
    const int cs  = rm - rs * CS;
    const int x0  = cs * OUTW;
    const int y0  = rs * ROWS;

    const size_t plane = (size_t)HH << LOG2W;
    const float* Ic = gi + (size_t)c * plane;
    const float* Pc = gp + (size_t)c * plane;
    float*       Qc = gq + (size_t)c * plane;

    const int  gx    = x0 - RAD + lane;
    const bool colok = (gx >= 0) && (gx < WW);
    const int  gxc   = min(max(gx, 0), WW - 1);
    const bool outl  = (lane >= RAD) && (lane < RAD + OUTW) && (gx < WW);
    const int  a_dn  = ((lane + RAD) & 63) << 2;
    const int  a_up  = ((lane - RAD - 1) & 63) << 2;
    const float nmsk = (lane >= RAD + 1) ? -1.0f : 0.0f;

    const int   nx     = min(gx + RAD, WW - 1) - max(gx - RAD, 0) + 1;
    const float inv_nx = __builtin_amdgcn_rcpf((float)max(nx, 1));

    float bi[17], bp[17];
    float si = 0.f, sp = 0.f, spi = 0.f, sii = 0.f;

    // ---- init: rows y0-8 .. y0+8 into circular buffer slots 0..16 ----
#pragma unroll
    for (int k = 0; k < 17; ++k) {
        int y = y0 - RAD + k;
        float a = 0.f, b = 0.f;
        if (y >= 0 && y < HH) {           // wave-uniform branch
            const float* rI = Ic + ((size_t)(unsigned)y << LOG2W);
            const float* rP = Pc + ((size_t)(unsigned)y << LOG2W);
            float av = rI[gxc];
            float bv = rP[gxc];
            a = colok ? av : 0.f;
            b = colok ? bv : 0.f;
        }
        bi[k] = a; bp[k] = b;
        si += a; sp += b; spi += a * b; sii += a * a;
    }

    // ---- emit one output row from current vertical sums ----
    auto emit = [&](int y, float icur) {
        float Si, Sp, Spi, Sii;
        scan4(si, sp, spi, sii, Si, Sp, Spi, Sii);
        float wi  = win17(Si,  a_dn, a_up, nmsk);
        float wp  = win17(Sp,  a_dn, a_up, nmsk);
        float wpi = win17(Spi, a_dn, a_up, nmsk);
        float wii = win17(Sii, a_dn, a_up, nmsk);

        int   ny   = min(y + RAD, HH - 1) - max(y - RAD, 0) + 1;   // uniform
        float invN = inv_nx * __builtin_amdgcn_rcpf((float)ny);
        float mi   = wi  * invN;
        float mp   = wp  * invN;
        float mpi  = wpi * invN;
        float mii  = wii * invN;
        float cip  = fmaf(-mp, mi, mpi);
        float cii  = fmaf(-mi, mi, mii);
        float a    = cip * __builtin_amdgcn_rcpf(cii + EPS);
        float b    = fmaf(-a, mi, mp);
        float q    = __builtin_amdgcn_fmed3f(fmaf(a, icur, b), 0.0f, 1.0f);
        if (outl) {
            float* Qrow = Qc + ((size_t)(unsigned)y << LOG2W);
            Qrow[gx] = q;
        }
    };

    emit(y0, bi[8]);                      // t = 0 (current row slot = 8); y0 < HH always

    int y = y0;
#pragma unroll 1
    for (int o = 0; o < 4; ++o) {
#pragma unroll
        for (int u = 0; u < 17; ++u) {
            ++y;                          // y = y0 + t, t = 1 + 17*o + u
            // outgoing row (y-9) lives in slot u; incoming row (y+8) reuses it
            float a0 = bi[u], b0 = bp[u];
            si -= a0; sp -= b0;
            spi = fmaf(-a0, b0, spi);
            sii = fmaf(-a0, a0, sii);

            int yin = y + RAD;
            float a = 0.f, b = 0.f;
            if (yin < HH) {               // wave-uniform; yin >= 9 always
                const float* rI = Ic + ((size_t)(unsigned)yin << LOG2W);
                const float* rP = Pc + ((size_t)(unsigned)yin << LOG2W);
                float av = rI[gxc];
                float bv = rP[gxc];
                a = colok ? av : 0.f;
                b = colok ? bv : 0.f;
            }
            bi[u] = a; bp[u] = b;
            si += a; sp += b;
            spi = fmaf(a, b, spi);
            sii = fmaf(a, a, sii);

            if (y < HH)                   // wave-uniform (only last row-strip trims)
                emit(y, bi[(u + 9) % 17]);  // current row y sits in slot (u+9)%17
        }
    }
}

extern "C" void kernel_launch(void* const* d_in, const int* in_sizes, int n_in,
                              void* d_out, int out_size, void* d_ws, size_t ws_size,
                              hipStream_t stream) {
    const float* gi = (const float*)d_in[0];
    const float* gp = (const float*)d_in[1];
    float* gq = (float*)d_out;
    const int total_waves = CC * CS * RS;          // 15480
    const int blocks = total_waves / WPB;          // 3870
    gf_stream_kernel<<<blocks, 256, 0, stream>>>(gi, gp, gq);
}